// Round 9
// baseline (751.013 us; speedup 1.0000x reference)
//
#include <hip/hip_runtime.h>
#include <hip/hip_cooperative_groups.h>
#include <cstdint>
#include <cstddef>

namespace cg = cooperative_groups;

// Problem constants (reference: B=4, N=2048, DIM=256, heads=8, groups=2)
#define B_    4
#define NPT   2048
#define DIM_  256
#define QKVW  768   // 3*DIM
#define XLEN  2097152   // 8192*256
#define QLEN  196608    // 768*256
#define PLEN  65536     // 256*256

typedef unsigned short ushort_t;
typedef short bf16x8 __attribute__((ext_vector_type(8)));
typedef float f32x4 __attribute__((ext_vector_type(4)));

// Fast gelu: A&S 7.1.26 erf (max abs err 1.5e-7).
__device__ __forceinline__ float gelu_fast(float x) {
  const float is2 = 0.70710678118654752440f;
  float z = x * is2;
  float az = __builtin_fabsf(z);
  float t = __builtin_amdgcn_rcpf(fmaf(0.3275911f, az, 1.0f));
  float p = fmaf(1.061405429f, t, -1.453152027f);
  p = fmaf(p, t, 1.421413741f);
  p = fmaf(p, t, -0.284496736f);
  p = fmaf(p, t, 0.254829592f);
  p = p * t;
  float e = __expf(-az * az);
  float er = fmaf(-p, e, 1.0f);
  er = __builtin_copysignf(er, x);
  return 0.5f * x * (1.0f + er);
}

// tanh-form gelu (~11 VALU; dev from erf-gelu ~1e-3 << 3.7e-2 threshold).
__device__ __forceinline__ float gelu_tanh(float x) {
  float x2 = x * x;
  float z2 = x * fmaf(0.0713548163f, x2, 1.5957691216f);
  float e = __expf(z2);
  float t = __builtin_amdgcn_rcpf(e + 1.0f);
  float th = fmaf(-2.0f, t, 1.0f);
  return 0.5f * x * (1.0f + th);
}

__device__ __forceinline__ ushort_t f2bf(float f) {
  unsigned u = __float_as_uint(f);
  unsigned r = (u + 0x7fffu + ((u >> 16) & 1u)) >> 16;
  return (ushort_t)r;
}
__device__ __forceinline__ float bf2f(ushort_t h) {
  return __uint_as_float(((unsigned)h) << 16);
}

template <int CTRL>
__device__ __forceinline__ void dppmin_step(int& lo, int& hi) {
  int olo = __builtin_amdgcn_update_dpp(lo, lo, CTRL, 0xf, 0xf, false);
  int ohi = __builtin_amdgcn_update_dpp(hi, hi, CTRL, 0xf, 0xf, false);
  unsigned long long o = ((unsigned long long)(unsigned)ohi << 32) | (unsigned)olo;
  unsigned long long c = ((unsigned long long)(unsigned)hi << 32) | (unsigned)lo;
  if (o < c) { lo = olo; hi = ohi; }
}
template <int CTRL>
__device__ __forceinline__ float dpp_addf(float x) {
  int s = __builtin_amdgcn_update_dpp(0, __float_as_int(x), CTRL, 0xf, 0xf, false);
  return x + __int_as_float(s);
}
__device__ __forceinline__ float head32_reduce(float u) {
  u = dpp_addf<0x111>(u);
  u = dpp_addf<0x112>(u);
  u = dpp_addf<0x114>(u);
  u = dpp_addf<0x118>(u);
  u = dpp_addf<0x142>(u);
  return u;
}

// scale a bf16x8 B-fragment by av[k] (8 consecutive k's), repack to bf16
__device__ __forceinline__ bf16x8 scale_bf(bf16x8 v, const float* avk) {
  bf16x8 r;
#pragma unroll
  for (int e = 0; e < 8; e++) {
    float f = bf2f((ushort_t)v[e]) * avk[e];
    r[e] = (short)f2bf(f);
  }
  return r;
}

// ---------------------------------------------------------------------------
// Register-file MFMA GEMM tile, 64x32, ONE wave, K=256, no LDS/barriers.
// A bf16 [M][256]; BT bf16 [N][256] (k-contig). Layout validated R6-R8
// end-to-end: A row=m0+i*16+r16, k=quad*8; C/D col=r16, row=quad*4+reg.
// MODE 0: C = acc               MODE 1: C = gelu(acc+bias), colsum atomics
// MODE 2: C = extra + (A@(B*av)) + bias   (av folded into B-frag in-register)
// ---------------------------------------------------------------------------
template <int MODE>
__device__ __forceinline__ void gemm_tile(
    const ushort_t* __restrict__ A, const ushort_t* __restrict__ BT,
    const float* __restrict__ bias, const float* __restrict__ extra,
    float* __restrict__ C, float* __restrict__ part, const float* avrow,
    int m0, int n0, int N, int lane) {
  constexpr int K = 256;
  int quad = lane >> 4, r16 = lane & 15;
  const ushort_t* Ap = A + (size_t)(m0 + r16) * K + quad * 8;
  const ushort_t* Bp = BT + (size_t)(n0 + r16) * K + quad * 8;
  f32x4 acc[4][2] = {};
  bf16x8 af[4], bf[2], af2[4], bf2[2];
#pragma unroll
  for (int i = 0; i < 4; i++) af[i] = *(const bf16x8*)(Ap + (size_t)i * 16 * K);
#pragma unroll
  for (int j = 0; j < 2; j++) bf[j] = *(const bf16x8*)(Bp + (size_t)j * 16 * K);
#pragma unroll
  for (int kc = 0; kc < 8; kc++) {
    if (kc < 7) {
      int ko = (kc + 1) * 32;
#pragma unroll
      for (int i = 0; i < 4; i++)
        af2[i] = *(const bf16x8*)(Ap + (size_t)i * 16 * K + ko);
#pragma unroll
      for (int j = 0; j < 2; j++)
        bf2[j] = *(const bf16x8*)(Bp + (size_t)j * 16 * K + ko);
    }
    bf16x8 b0 = bf[0], b1 = bf[1];
    if (MODE == 2) {
      const float* avk = avrow + kc * 32 + quad * 8;  // LDS, quad-broadcast
      b0 = scale_bf(b0, avk);
      b1 = scale_bf(b1, avk);
    }
#pragma unroll
    for (int i = 0; i < 4; i++) {
      acc[i][0] = __builtin_amdgcn_mfma_f32_16x16x32_bf16(af[i], b0, acc[i][0], 0, 0, 0);
      acc[i][1] = __builtin_amdgcn_mfma_f32_16x16x32_bf16(af[i], b1, acc[i][1], 0, 0, 0);
    }
#pragma unroll
    for (int i = 0; i < 4; i++) af[i] = af2[i];
    bf[0] = bf2[0]; bf[1] = bf2[1];
  }
  int batch = m0 >> 11;
  float cs[2] = {};
#pragma unroll
  for (int i = 0; i < 4; i++) {
#pragma unroll
    for (int j = 0; j < 2; j++) {
      int col = n0 + j * 16 + r16;
#pragma unroll
      for (int r = 0; r < 4; r++) {
        int row = m0 + i * 16 + quad * 4 + r;
        float v = acc[i][j][r];
        if (MODE == 1) { v = gelu_fast(v + bias[col]); cs[j] += v; }
        else if (MODE == 2) v = extra[(size_t)row * 256 + col] + v + bias[col];
        C[(size_t)row * N + col] = v;
      }
    }
  }
  if (MODE == 1) {
#pragma unroll
    for (int j = 0; j < 2; j++) {
      cs[j] += __shfl_xor(cs[j], 16, 64);
      cs[j] += __shfl_xor(cs[j], 32, 64);
    }
    if (quad == 0) {
#pragma unroll
      for (int j = 0; j < 2; j++)
        atomicAdd(&part[batch * 256 + n0 + j * 16 + r16], cs[j]);
    }
  }
}

// ---------------------------------------------------------------------------
// Attention body for one (b,n), one group, per-wave LDS staging (wave-private
// regions; no block barrier). Folded logits via 32-lane DPP reduce.
// ---------------------------------------------------------------------------
template <int NK>
__device__ __forceinline__ float attn_group_m(
    const float* __restrict__ qkvb, const int* sidx, const float4* srel,
    float (*slog)[32], float qS, float w0, float w1, float w2, float bb, int t) {
  float rp[NK];
  int lane = t & 63;
  bool writer = ((lane & 31) == 31);
  int h = t >> 5;
#pragma unroll
  for (int j = 0; j < NK; j++) {
    int jj = __builtin_amdgcn_readfirstlane(sidx[j]);   // LDS broadcast -> SGPR
    float4 rr = srel[j];                                // ds_read_b128 broadcast
    const float* kr = qkvb + (size_t)jj * QKVW + 256;
    float kv = kr[t];                                   // coalesced
    float xx = fmaf(rr.x, w0, fmaf(rr.y, w1, fmaf(rr.z, w2, bb)));
    float r = gelu_tanh(xx);
    rp[j] = r;
    float u = head32_reduce(fmaf(qS, kv, r));
    if (writer) slog[h][j] = u;
  }
  __builtin_amdgcn_wave_barrier();
  asm volatile("s_waitcnt lgkmcnt(0)" ::: "memory");
  float mx = -3.4e38f;
#pragma unroll
  for (int j = 0; j < NK; j++) mx = fmaxf(mx, slog[h][j]);
  float num = 0.f, den = 0.f;
#pragma unroll
  for (int j = 0; j < NK; j++) {
    float e = __expf(slog[h][j] - mx);
    int jj = __builtin_amdgcn_readfirstlane(sidx[j]);
    const float* vr = qkvb + (size_t)jj * QKVW + 512;
    float v = vr[t];
    num = fmaf(e, v + rp[j], num);
    den += e;
  }
  return num * __builtin_amdgcn_rcpf(den);
}

// ---------------------------------------------------------------------------
// THE MEGA KERNEL: whole network, one launch, 4 grid syncs. All phases are
// grid-stride so any co-resident grid size works.
// R8 ERRATUM: __launch_bounds__(256,4) capped VGPR at 64 -> knn's keys[32]
// (64 VGPRs of u64) spilled to scratch: +370 MB HBM traffic, VALUBusy 15%,
// 776 µs. Fix: (256,3) -> VGPR cap ~168 >= the ~110 phase-1 demand, still
// guarantees >=3 blocks/CU for the attention phase.
// ---------------------------------------------------------------------------
__global__ __launch_bounds__(256, 3) void mega_kernel(
    const float* __restrict__ x, const float* __restrict__ pos,
    const float* __restrict__ Wqkv, const float* __restrict__ Wp0,
    const float* __restrict__ bp0, const float* __restrict__ Wp1,
    const float* __restrict__ bp1, const float* __restrict__ Wproj,
    const float* __restrict__ bproj, const float* __restrict__ Wfc1,
    const float* __restrict__ bfc1, const float* __restrict__ Wfc2,
    const float* __restrict__ bfc2, const float* __restrict__ Whead,
    const float* __restrict__ bhead, float* __restrict__ out,
    int* __restrict__ knnidx, float* __restrict__ qkv,
    ushort_t* __restrict__ xbf, ushort_t* __restrict__ WqkvT,
    ushort_t* __restrict__ WprojT, ushort_t* __restrict__ WheadT,
    float* __restrict__ part) {
  cg::grid_group grid = cg::this_grid();
  const int tid = threadIdx.x;
  const int nblk = gridDim.x;
  const int gtid = blockIdx.x * 256 + tid;
  const int nthr = nblk * 256;
  const int wave = tid >> 6, lane = tid & 63;
  const int gwave = blockIdx.x * 4 + wave;
  const int W = nblk * 4;

  __shared__ int s_idx[4][32];
  __shared__ float4 s_rel[4][32];
  __shared__ float s_log[8][32];
  __shared__ float s_S[1024];
  __shared__ float s_Z[512];
  __shared__ float s_A[1024];
  __shared__ float s_av[1024];

  // ===== Phase 1: convert + part-zero + KNN =====
  if (gtid < 1024) part[gtid] = 0.f;
  for (int i = gtid; i < XLEN + QLEN + 2 * PLEN; i += nthr) {
    if (i < XLEN) {
      xbf[i] = f2bf(x[i]);
    } else if (i < XLEN + QLEN) {
      int e = i - XLEN; int n = e >> 8, k = e & 255;
      WqkvT[e] = f2bf(Wqkv[k * 768 + n]);
    } else if (i < XLEN + QLEN + PLEN) {
      int e = i - XLEN - QLEN; int n = e >> 8, k = e & 255;
      WprojT[e] = f2bf(Wproj[k * 256 + n]);
    } else {
      int e = i - XLEN - QLEN - PLEN; int n = e >> 8, k = e & 255;
      WheadT[e] = f2bf(Whead[k * 256 + n]);
    }
  }
  for (int wq = gwave; wq < 8192; wq += W) {
    int b = wq >> 11, n = wq & (NPT - 1);
    const float* pb = pos + (size_t)b * NPT * 3;
    float qx = pb[n * 3 + 0], qy = pb[n * 3 + 1], qz = pb[n * 3 + 2];
    unsigned long long keys[32];
    {
#pragma clang fp contract(off)
#pragma unroll
      for (int s = 0; s < 32; s++) {
        int j = lane + (s << 6);
        float dx = qx - pb[j * 3 + 0];
        float dy = qy - pb[j * 3 + 1];
        float dz = qz - pb[j * 3 + 2];
        float d = dx * dx;
        d = d + dy * dy;
        d = d + dz * dz;
        keys[s] = ((unsigned long long)__float_as_uint(d) << 32) | (unsigned int)j;
      }
    }
    unsigned long long gk[4];
#pragma unroll
    for (int gi = 0; gi < 4; gi++) {
      unsigned long long m = keys[gi * 8];
#pragma unroll
      for (int s = 1; s < 8; s++) {
        unsigned long long c = keys[gi * 8 + s];
        m = (c < m) ? c : m;
      }
      gk[gi] = m;
    }
    unsigned long long lkey = gk[0];
#pragma unroll
    for (int gi = 1; gi < 4; gi++) lkey = (gk[gi] < lkey) ? gk[gi] : lkey;
    int* outp = knnidx + (size_t)wq * 32;
    for (int r = 0; r < 32; r++) {
      int lo = (int)(unsigned)(lkey & 0xffffffffULL);
      int hi = (int)(unsigned)(lkey >> 32);
      dppmin_step<0x111>(lo, hi);
      dppmin_step<0x112>(lo, hi);
      dppmin_step<0x114>(lo, hi);
      dppmin_step<0x118>(lo, hi);
      dppmin_step<0x142>(lo, hi);
      dppmin_step<0x143>(lo, hi);
      unsigned int glo = (unsigned int)__builtin_amdgcn_readlane(lo, 63);
      unsigned int ghi = (unsigned int)__builtin_amdgcn_readlane(hi, 63);
      unsigned long long g = ((unsigned long long)ghi << 32) | glo;
      if (lkey == g) {
        outp[r] = (int)glo;
#pragma unroll
        for (int gi = 0; gi < 4; gi++) {
          if (gk[gi] == g) {
            unsigned long long m = ~0ULL;
#pragma unroll
            for (int s = 0; s < 8; s++) {
              unsigned long long c = keys[gi * 8 + s];
              if (c == g) { c = ~0ULL; keys[gi * 8 + s] = c; }
              m = (c < m) ? c : m;
            }
            gk[gi] = m;
          }
        }
        lkey = gk[0];
#pragma unroll
        for (int gi = 1; gi < 4; gi++) lkey = (gk[gi] < lkey) ? gk[gi] : lkey;
      }
    }
  }
  grid.sync();

  // ===== Phase 2: qkv GEMM (8192x768x256), 3072 64x32 tiles =====
  for (int t0 = gwave; t0 < 3072; t0 += W) {
    int m0 = (t0 / 24) * 64, n0 = (t0 % 24) * 32;
    gemm_tile<0>(xbf, WqkvT, nullptr, nullptr, qkv, nullptr, nullptr,
                 m0, n0, QKVW, lane);
  }
  grid.sync();

  // ===== Phase 3: attention (xcat overwrites xbf region) =====
  {
    const float SCALE = 0.17677669529663687f;  // 32^-0.5
    int g = tid >> 7, c = tid & 127;
    const float* Wp = g ? Wp1 : Wp0;
    const float* bp = g ? bp1 : bp0;
    float w0 = Wp[c], w1 = Wp[128 + c], w2 = Wp[256 + c], bb = bp[c];
    for (int u = blockIdx.x; u < 8192; u += nblk) {
      int b = u >> 11, n = u & (NPT - 1);
      const float* qkvb = qkv + (size_t)b * NPT * QKVW;
      if (lane < 32) {
        int j = knnidx[(size_t)u * 32 + lane];
        s_idx[wave][lane] = j;
        const float* pn = pos + ((size_t)b * NPT + n) * 3;
        const float* pj = pos + ((size_t)b * NPT + j) * 3;
        s_rel[wave][lane] = make_float4(pn[0] - pj[0], pn[1] - pj[1],
                                        pn[2] - pj[2], 0.f);
      }
      __builtin_amdgcn_wave_barrier();
      asm volatile("s_waitcnt lgkmcnt(0)" ::: "memory");
      float q = qkvb[(size_t)n * QKVW + tid];
      float qS = q * SCALE;
      float o = (g == 0)
          ? attn_group_m<16>(qkvb, s_idx[wave], s_rel[wave], s_log,
                             qS, w0, w1, w2, bb, tid)
          : attn_group_m<32>(qkvb, s_idx[wave], s_rel[wave], s_log,
                             qS, w0, w1, w2, bb, tid);
      xbf[(size_t)u * DIM_ + tid] = f2bf(o);  // xcat
    }
  }
  grid.sync();

  // ===== Phase 4: proj GEMM + gelu + fused colsum (fp overwrites qkv) =====
  for (int t0 = gwave; t0 < 1024; t0 += W) {
    int m0 = (t0 >> 3) * 64, n0 = (t0 & 7) * 32;
    gemm_tile<1>(xbf, WprojT, bproj, nullptr, qkv, part, nullptr,
                 m0, n0, DIM_, lane);
  }
  grid.sync();

  // ===== Phase 5: av-MLP (redundant per block, block-local) + head GEMM ====
  for (int i = tid; i < 1024; i += 256) s_S[i] = part[i] * (1.0f / 2048.0f);
  __syncthreads();
#pragma unroll
  for (int it = 0; it < 2; it++) {
    int item = tid + 256 * it; int bb2 = item >> 7, tt = item & 127;
    float z = bfc1[tt];
    for (int i = 0; i < 256; i++) z += s_S[bb2 * 256 + i] * Wfc1[i * 128 + tt];
    s_Z[item] = gelu_fast(z);
  }
  __syncthreads();
#pragma unroll
  for (int it = 0; it < 4; it++) {
    int item = tid + 256 * it; int bb2 = item >> 8, tt = item & 255;
    float a = bfc2[tt];
    for (int jx = 0; jx < 128; jx++) a += s_Z[bb2 * 128 + jx] * Wfc2[jx * 256 + tt];
    s_A[item] = a;
  }
  __syncthreads();
#pragma unroll
  for (int it = 0; it < 4; it++) {
    int item = tid + 256 * it; int bb2 = item >> 8, tt = item & 255;
    float a = s_A[item], pA = s_A[bb2 * 256 + (tt ^ 128)];
    float m = fmaxf(a, pA);
    float e = __expf(a - m);
    s_av[item] = e / (e + __expf(pA - m));
  }
  __syncthreads();
  for (int t0 = gwave; t0 < 1024; t0 += W) {
    int m0 = (t0 >> 3) * 64, n0 = (t0 & 7) * 32;
    gemm_tile<2>(xbf, WheadT, bhead, qkv, out, nullptr,
                 &s_av[(m0 >> 11) * 256], m0, n0, DIM_, lane);
  }
}

// ---------------------------------------------------------------------------
extern "C" void kernel_launch(void* const* d_in, const int* in_sizes, int n_in,
                              void* d_out, int out_size, void* d_ws, size_t ws_size,
                              hipStream_t stream) {
  const float* x     = (const float*)d_in[0];
  const float* pos   = (const float*)d_in[1];
  const float* Wqkv  = (const float*)d_in[2];
  const float* Wp0   = (const float*)d_in[3];
  const float* bp0   = (const float*)d_in[4];
  const float* Wp1   = (const float*)d_in[5];
  const float* bp1   = (const float*)d_in[6];
  const float* Wproj = (const float*)d_in[7];
  const float* bproj = (const float*)d_in[8];
  const float* Wfc1  = (const float*)d_in[9];
  const float* bfc1  = (const float*)d_in[10];
  const float* Wfc2  = (const float*)d_in[11];
  const float* bfc2  = (const float*)d_in[12];
  const float* Whead = (const float*)d_in[13];
  const float* bhead = (const float*)d_in[14];
  float* out = (float*)d_out;

  char* ws = (char*)d_ws;
  size_t off = 0;
  int* idx = (int*)(ws + off);              off += (size_t)B_ * NPT * 32 * 4;   // 1.0 MB
  float* qkv = (float*)(ws + off);          off += (size_t)B_ * NPT * QKVW * 4; // 25.2 MB (also fp)
  ushort_t* xbf = (ushort_t*)(ws + off);    off += (size_t)B_ * NPT * DIM_ * 2; // 4.2 MB (also xcat)
  ushort_t* WqkvT = (ushort_t*)(ws + off);  off += (size_t)QLEN * 2;
  ushort_t* WprojT = (ushort_t*)(ws + off); off += (size_t)PLEN * 2;
  ushort_t* WheadT = (ushort_t*)(ws + off); off += (size_t)PLEN * 2;
  float* part = (float*)(ws + off);         off += 1024 * 4;

  int maxb = 0;
  hipOccupancyMaxActiveBlocksPerMultiprocessor(&maxb, mega_kernel, 256, 0);
  if (maxb < 1) maxb = 1;
  if (maxb > 8) maxb = 8;
  int nblk = maxb * 256;  // 256 CUs on MI355X; co-residency per occupancy API

  void* args[] = {
      (void*)&x, (void*)&pos, (void*)&Wqkv, (void*)&Wp0, (void*)&bp0,
      (void*)&Wp1, (void*)&bp1, (void*)&Wproj, (void*)&bproj,
      (void*)&Wfc1, (void*)&bfc1, (void*)&Wfc2, (void*)&bfc2,
      (void*)&Whead, (void*)&bhead, (void*)&out,
      (void*)&idx, (void*)&qkv, (void*)&xbf, (void*)&WqkvT,
      (void*)&WprojT, (void*)&WheadT, (void*)&part};
  hipLaunchCooperativeKernel((void*)mega_kernel, dim3(nblk), dim3(256),
                             args, 0, stream);
}

// Round 10
// 281.024 us; speedup vs baseline: 2.6724x; 2.6724x over previous
//
#include <hip/hip_runtime.h>
#include <cstdint>
#include <cstddef>

// Problem constants (reference: B=4, N=2048, DIM=256, heads=8, groups=2)
#define B_    4
#define NPT   2048
#define DIM_  256
#define QKVW  768   // 3*DIM
#define XLEN  2097152   // 8192*256
#define QLEN  196608    // 768*256
#define PLEN  65536     // 256*256
#define TOTC  (XLEN + QLEN + 2 * PLEN)  // 2424832

typedef unsigned short ushort_t;
typedef short bf16x8 __attribute__((ext_vector_type(8)));
typedef float f32x4 __attribute__((ext_vector_type(4)));

__device__ __forceinline__ float gelu_f(float x) {
  return 0.5f * x * (1.0f + erff(x * 0.70710678118654752440f));
}

// Fast gelu: A&S 7.1.26 erf (max abs err 1.5e-7).
__device__ __forceinline__ float gelu_fast(float x) {
  const float is2 = 0.70710678118654752440f;
  float z = x * is2;
  float az = __builtin_fabsf(z);
  float t = __builtin_amdgcn_rcpf(fmaf(0.3275911f, az, 1.0f));
  float p = fmaf(1.061405429f, t, -1.453152027f);
  p = fmaf(p, t, 1.421413741f);
  p = fmaf(p, t, -0.284496736f);
  p = fmaf(p, t, 0.254829592f);
  p = p * t;
  float e = __expf(-az * az);
  float er = fmaf(-p, e, 1.0f);
  er = __builtin_copysignf(er, x);
  return 0.5f * x * (1.0f + er);
}

// tanh-form gelu (~11 VALU; dev from erf-gelu ~1e-3 << 3.7e-2 threshold).
__device__ __forceinline__ float gelu_tanh(float x) {
  float x2 = x * x;
  float z2 = x * fmaf(0.0713548163f, x2, 1.5957691216f);
  float e = __expf(z2);
  float t = __builtin_amdgcn_rcpf(e + 1.0f);
  float th = fmaf(-2.0f, t, 1.0f);
  return 0.5f * x * (1.0f + th);
}

__device__ __forceinline__ ushort_t f2bf(float f) {
  unsigned u = __float_as_uint(f);
  unsigned r = (u + 0x7fffu + ((u >> 16) & 1u)) >> 16;
  return (ushort_t)r;
}
__device__ __forceinline__ float bf2f(ushort_t h) {
  return __uint_as_float(((unsigned)h) << 16);
}

template <int CTRL>
__device__ __forceinline__ void dppmin_step(int& lo, int& hi) {
  int olo = __builtin_amdgcn_update_dpp(lo, lo, CTRL, 0xf, 0xf, false);
  int ohi = __builtin_amdgcn_update_dpp(hi, hi, CTRL, 0xf, 0xf, false);
  unsigned long long o = ((unsigned long long)(unsigned)ohi << 32) | (unsigned)olo;
  unsigned long long c = ((unsigned long long)(unsigned)hi << 32) | (unsigned)lo;
  if (o < c) { lo = olo; hi = ohi; }
}
template <int CTRL>
__device__ __forceinline__ float dpp_addf(float x) {
  int s = __builtin_amdgcn_update_dpp(0, __float_as_int(x), CTRL, 0xf, 0xf, false);
  return x + __int_as_float(s);
}
__device__ __forceinline__ float head32_reduce(float u) {
  u = dpp_addf<0x111>(u);
  u = dpp_addf<0x112>(u);
  u = dpp_addf<0x114>(u);
  u = dpp_addf<0x118>(u);
  u = dpp_addf<0x142>(u);
  return u;
}

// scale a bf16x8 B-fragment by av[k] (8 consecutive k's from global, L1-hot)
__device__ __forceinline__ bf16x8 scale_bf(bf16x8 v, const float* avk) {
  bf16x8 r;
#pragma unroll
  for (int e = 0; e < 8; e++) {
    float f = bf2f((ushort_t)v[e]) * avk[e];
    r[e] = (short)f2bf(f);
  }
  return r;
}

// ---------------------------------------------------------------------------
// PREP: fused KNN + convert (independent work, disjoint block ranges).
// Blocks 0..2047: KNN, one wave per query (DPP wave-min, packed u64 keys).
// Blocks 2048..4095: grid-stride bf16 convert (coalesced reads, strided
// writes for the W transposes) + part zero.
// ---------------------------------------------------------------------------
__global__ __launch_bounds__(256) void prep_kernel(
    const float* __restrict__ pos, const float* __restrict__ x,
    const float* __restrict__ Wqkv, const float* __restrict__ Wproj,
    const float* __restrict__ Whead, int* __restrict__ idx_out,
    ushort_t* __restrict__ xbf, ushort_t* __restrict__ WqkvT,
    ushort_t* __restrict__ WprojT, ushort_t* __restrict__ WheadT,
    float* __restrict__ part) {
  int tid = threadIdx.x;
  if (blockIdx.x >= 2048) {
    // ---- convert path ----
    int base = (blockIdx.x - 2048) * 256 + tid;
    if (base < 1024) part[base] = 0.f;
    for (int i = base; i < TOTC; i += 2048 * 256) {
      if (i < XLEN) {
        xbf[i] = f2bf(x[i]);
      } else if (i < XLEN + QLEN) {
        int e = i - XLEN;                  // input-major: coalesced read
        int k = e / 768, n = e - k * 768;
        WqkvT[n * 256 + k] = f2bf(Wqkv[e]);
      } else if (i < XLEN + QLEN + PLEN) {
        int e = i - XLEN - QLEN;
        int k = e >> 8, n = e & 255;
        WprojT[n * 256 + k] = f2bf(Wproj[e]);
      } else {
        int e = i - XLEN - QLEN - PLEN;
        int k = e >> 8, n = e & 255;
        WheadT[n * 256 + k] = f2bf(Whead[e]);
      }
    }
    return;
  }
  // ---- KNN path ----
  int wave = tid >> 6, lane = tid & 63;
  int wq = blockIdx.x * 4 + wave;
  int b = wq >> 11, n = wq & (NPT - 1);
  const float* pb = pos + (size_t)b * NPT * 3;
  float qx = pb[n * 3 + 0], qy = pb[n * 3 + 1], qz = pb[n * 3 + 2];
  unsigned long long keys[32];
  {
#pragma clang fp contract(off)
#pragma unroll
    for (int s = 0; s < 32; s++) {
      int j = lane + (s << 6);
      float dx = qx - pb[j * 3 + 0];
      float dy = qy - pb[j * 3 + 1];
      float dz = qz - pb[j * 3 + 2];
      float d = dx * dx;
      d = d + dy * dy;
      d = d + dz * dz;
      keys[s] = ((unsigned long long)__float_as_uint(d) << 32) | (unsigned int)j;
    }
  }
  unsigned long long gk[4];
#pragma unroll
  for (int gi = 0; gi < 4; gi++) {
    unsigned long long m = keys[gi * 8];
#pragma unroll
    for (int s = 1; s < 8; s++) {
      unsigned long long c = keys[gi * 8 + s];
      m = (c < m) ? c : m;
    }
    gk[gi] = m;
  }
  unsigned long long lkey = gk[0];
#pragma unroll
  for (int gi = 1; gi < 4; gi++) lkey = (gk[gi] < lkey) ? gk[gi] : lkey;
  int* outp = idx_out + (size_t)wq * 32;
  for (int r = 0; r < 32; r++) {
    int lo = (int)(unsigned)(lkey & 0xffffffffULL);
    int hi = (int)(unsigned)(lkey >> 32);
    dppmin_step<0x111>(lo, hi);
    dppmin_step<0x112>(lo, hi);
    dppmin_step<0x114>(lo, hi);
    dppmin_step<0x118>(lo, hi);
    dppmin_step<0x142>(lo, hi);
    dppmin_step<0x143>(lo, hi);
    unsigned int glo = (unsigned int)__builtin_amdgcn_readlane(lo, 63);
    unsigned int ghi = (unsigned int)__builtin_amdgcn_readlane(hi, 63);
    unsigned long long g = ((unsigned long long)ghi << 32) | glo;
    if (lkey == g) {
      outp[r] = (int)glo;
#pragma unroll
      for (int gi = 0; gi < 4; gi++) {
        if (gk[gi] == g) {
          unsigned long long m = ~0ULL;
#pragma unroll
          for (int s = 0; s < 8; s++) {
            unsigned long long c = keys[gi * 8 + s];
            if (c == g) { c = ~0ULL; keys[gi * 8 + s] = c; }
            m = (c < m) ? c : m;
          }
          gk[gi] = m;
        }
      }
      lkey = gk[0];
#pragma unroll
      for (int gi = 1; gi < 4; gi++) lkey = (gk[gi] < lkey) ? gk[gi] : lkey;
    }
  }
}

// ---------------------------------------------------------------------------
// Register-file MFMA GEMM: ONE 64-thread wave per 64x32 tile, K=256. No LDS,
// no barriers; software-pipelined dwordx4 loads; latency hidden by TLP
// (3072/1024 one-wave blocks). Layout validated R6-R9 end-to-end.
// MODE 0: C = acc                     (qkv, N=768)
// MODE 1: C = gelu(acc+bias), colsum atomics into part  (feats_proj)
// MODE 2: C = extra + (A@(B*av)) + bias   (av from global, L1-hot)
// ---------------------------------------------------------------------------
template <int MODE>
__global__ __launch_bounds__(64, 4) void gemm_rf(
    const ushort_t* __restrict__ A, const ushort_t* __restrict__ BT,
    const float* __restrict__ bias, const float* __restrict__ extra,
    float* __restrict__ C, float* __restrict__ part,
    const float* __restrict__ av, int N) {
  constexpr int K = 256;
  int lane = threadIdx.x;
  int quad = lane >> 4, r16 = lane & 15;
  int t0 = blockIdx.x;
  int m0, n0;
  if (MODE == 0) { m0 = (t0 / 24) * 64; n0 = (t0 % 24) * 32; }
  else           { m0 = (t0 >> 3) * 64; n0 = (t0 & 7) * 32; }
  int batch = m0 >> 11;
  const ushort_t* Ap = A + (size_t)(m0 + r16) * K + quad * 8;
  const ushort_t* Bp = BT + (size_t)(n0 + r16) * K + quad * 8;
  f32x4 acc[4][2] = {};
  bf16x8 af[4], bf[2], af2[4], bf2[2];
#pragma unroll
  for (int i = 0; i < 4; i++) af[i] = *(const bf16x8*)(Ap + (size_t)i * 16 * K);
#pragma unroll
  for (int j = 0; j < 2; j++) bf[j] = *(const bf16x8*)(Bp + (size_t)j * 16 * K);
#pragma unroll
  for (int kc = 0; kc < 8; kc++) {
    if (kc < 7) {
      int ko = (kc + 1) * 32;
#pragma unroll
      for (int i = 0; i < 4; i++)
        af2[i] = *(const bf16x8*)(Ap + (size_t)i * 16 * K + ko);
#pragma unroll
      for (int j = 0; j < 2; j++)
        bf2[j] = *(const bf16x8*)(Bp + (size_t)j * 16 * K + ko);
    }
    bf16x8 b0 = bf[0], b1 = bf[1];
    if (MODE == 2) {
      const float* avk = av + batch * 256 + kc * 32 + quad * 8;
      b0 = scale_bf(b0, avk);
      b1 = scale_bf(b1, avk);
    }
#pragma unroll
    for (int i = 0; i < 4; i++) {
      acc[i][0] = __builtin_amdgcn_mfma_f32_16x16x32_bf16(af[i], b0, acc[i][0], 0, 0, 0);
      acc[i][1] = __builtin_amdgcn_mfma_f32_16x16x32_bf16(af[i], b1, acc[i][1], 0, 0, 0);
    }
#pragma unroll
    for (int i = 0; i < 4; i++) af[i] = af2[i];
    bf[0] = bf2[0]; bf[1] = bf2[1];
  }
  float cs[2] = {};
#pragma unroll
  for (int i = 0; i < 4; i++) {
#pragma unroll
    for (int j = 0; j < 2; j++) {
      int col = n0 + j * 16 + r16;
#pragma unroll
      for (int r = 0; r < 4; r++) {
        int row = m0 + i * 16 + quad * 4 + r;
        float v = acc[i][j][r];
        if (MODE == 1) { v = gelu_fast(v + bias[col]); cs[j] += v; }
        else if (MODE == 2) v = extra[(size_t)row * 256 + col] + v + bias[col];
        C[(size_t)row * N + col] = v;
      }
    }
  }
  if (MODE == 1) {
#pragma unroll
    for (int j = 0; j < 2; j++) {
      cs[j] += __shfl_xor(cs[j], 16, 64);
      cs[j] += __shfl_xor(cs[j], 32, 64);
    }
    if (quad == 0) {
#pragma unroll
      for (int j = 0; j < 2; j++)
        atomicAdd(&part[batch * 256 + n0 + j * 16 + r16], cs[j]);
    }
  }
}

// ---------------------------------------------------------------------------
// Attention (R8-phase3 form, standalone): block=256 = one (b,n), thread t =
// qkv channel; per-wave LDS staging of idx/rel (no block barrier), folded
// logits via 32-lane DPP reduce, SGPR-base gathers, tanh gelu. Output bf16.
// ---------------------------------------------------------------------------
template <int NK>
__device__ __forceinline__ float attn_group_m(
    const float* __restrict__ qkvb, const int* sidx, const float4* srel,
    float (*slog)[32], float qS, float w0, float w1, float w2, float bb, int t) {
  float rp[NK];
  int lane = t & 63;
  bool writer = ((lane & 31) == 31);
  int h = t >> 5;
#pragma unroll
  for (int j = 0; j < NK; j++) {
    int jj = __builtin_amdgcn_readfirstlane(sidx[j]);   // LDS broadcast -> SGPR
    float4 rr = srel[j];                                // ds_read_b128 broadcast
    const float* kr = qkvb + (size_t)jj * QKVW + 256;
    float kv = kr[t];                                   // coalesced
    float xx = fmaf(rr.x, w0, fmaf(rr.y, w1, fmaf(rr.z, w2, bb)));
    float r = gelu_tanh(xx);
    rp[j] = r;
    float u = head32_reduce(fmaf(qS, kv, r));
    if (writer) slog[h][j] = u;
  }
  __builtin_amdgcn_wave_barrier();
  asm volatile("s_waitcnt lgkmcnt(0)" ::: "memory");
  float mx = -3.4e38f;
#pragma unroll
  for (int j = 0; j < NK; j++) mx = fmaxf(mx, slog[h][j]);
  float num = 0.f, den = 0.f;
#pragma unroll
  for (int j = 0; j < NK; j++) {
    float e = __expf(slog[h][j] - mx);
    int jj = __builtin_amdgcn_readfirstlane(sidx[j]);
    const float* vr = qkvb + (size_t)jj * QKVW + 512;
    float v = vr[t];
    num = fmaf(e, v + rp[j], num);
    den += e;
  }
  return num * __builtin_amdgcn_rcpf(den);
}

__global__ __launch_bounds__(256) void attn_kernel(
    const float* __restrict__ qkv, const float* __restrict__ pos,
    const int* __restrict__ knn,
    const float* __restrict__ Wp0, const float* __restrict__ bp0,
    const float* __restrict__ Wp1, const float* __restrict__ bp1,
    ushort_t* __restrict__ xcat) {
  const float SCALE = 0.17677669529663687f;  // 32^-0.5
  int u = blockIdx.x;
  int b = u >> 11, n = u & (NPT - 1);
  int tid = threadIdx.x;
  int g = tid >> 7, c = tid & 127;
  int wave = tid >> 6, lane = tid & 63;
  __shared__ int s_idx[4][32];
  __shared__ float4 s_rel[4][32];
  __shared__ float s_log[8][32];
  const float* qkvb = qkv + (size_t)b * NPT * QKVW;
  if (lane < 32) {
    int j = knn[(size_t)u * 32 + lane];
    s_idx[wave][lane] = j;
    const float* pn = pos + ((size_t)b * NPT + n) * 3;
    const float* pj = pos + ((size_t)b * NPT + j) * 3;
    s_rel[wave][lane] = make_float4(pn[0] - pj[0], pn[1] - pj[1],
                                    pn[2] - pj[2], 0.f);
  }
  __builtin_amdgcn_wave_barrier();
  asm volatile("s_waitcnt lgkmcnt(0)" ::: "memory");
  float q = qkvb[(size_t)n * QKVW + tid];
  const float* Wp = g ? Wp1 : Wp0;
  const float* bp = g ? bp1 : bp0;
  float w0 = Wp[c], w1 = Wp[128 + c], w2 = Wp[256 + c], bb = bp[c];
  float qS = q * SCALE;
  float o = (g == 0)
      ? attn_group_m<16>(qkvb, s_idx[wave], s_rel[wave], s_log,
                         qS, w0, w1, w2, bb, tid)
      : attn_group_m<32>(qkvb, s_idx[wave], s_rel[wave], s_log,
                         qS, w0, w1, w2, bb, tid);
  xcat[((size_t)b * NPT + n) * DIM_ + tid] = f2bf(o);
}

// ---------------------------------------------------------------------------
// MSF av only: S = part/2048 -> Z = gelu(S@Wfc1+b) -> a = Z@Wfc2+b ->
// av = pairwise softmax. One block per batch; av to global (gemm2 reads it).
// ---------------------------------------------------------------------------
__global__ __launch_bounds__(256) void msf_av_kernel(
    const float* __restrict__ part, const float* __restrict__ Wfc1,
    const float* __restrict__ bfc1, const float* __restrict__ Wfc2,
    const float* __restrict__ bfc2, float* __restrict__ av_out) {
  int b = blockIdx.x, t = threadIdx.x;
  __shared__ float S[256], Z[128], A[256];
  S[t] = part[b * 256 + t] * (1.0f / 2048.0f);
  __syncthreads();
  if (t < 128) {
    float z = bfc1[t];
    for (int i = 0; i < 256; i++) z += S[i] * Wfc1[i * 128 + t];
    Z[t] = gelu_f(z);
  }
  __syncthreads();
  float a = bfc2[t];
  for (int j = 0; j < 128; j++) a += Z[j] * Wfc2[j * 256 + t];
  A[t] = a;
  __syncthreads();
  float pA = A[t ^ 128];
  float m = fmaxf(a, pA);
  float e = expf(a - m);
  av_out[b * 256 + t] = e / (e + expf(pA - m));
}

// ---------------------------------------------------------------------------
extern "C" void kernel_launch(void* const* d_in, const int* in_sizes, int n_in,
                              void* d_out, int out_size, void* d_ws, size_t ws_size,
                              hipStream_t stream) {
  const float* x     = (const float*)d_in[0];
  const float* pos   = (const float*)d_in[1];
  const float* Wqkv  = (const float*)d_in[2];
  const float* Wp0   = (const float*)d_in[3];
  const float* bp0   = (const float*)d_in[4];
  const float* Wp1   = (const float*)d_in[5];
  const float* bp1   = (const float*)d_in[6];
  const float* Wproj = (const float*)d_in[7];
  const float* bproj = (const float*)d_in[8];
  const float* Wfc1  = (const float*)d_in[9];
  const float* bfc1  = (const float*)d_in[10];
  const float* Wfc2  = (const float*)d_in[11];
  const float* bfc2  = (const float*)d_in[12];
  const float* Whead = (const float*)d_in[13];
  const float* bhead = (const float*)d_in[14];
  float* out = (float*)d_out;

  char* ws = (char*)d_ws;
  size_t off = 0;
  int* idx = (int*)(ws + off);              off += (size_t)B_ * NPT * 32 * 4;   // 1.0 MB
  float* qkv = (float*)(ws + off);          off += (size_t)B_ * NPT * QKVW * 4; // 25.2 MB (also fp)
  float* fp = qkv;  // feats_proj reuses qkv region (qkv dead after attn)
  ushort_t* xbf = (ushort_t*)(ws + off);    off += (size_t)B_ * NPT * DIM_ * 2; // 4.2 MB
  ushort_t* xcat = xbf;  // xbf dead after gemm0
  ushort_t* WqkvT = (ushort_t*)(ws + off);  off += (size_t)QLEN * 2;
  ushort_t* WprojT = (ushort_t*)(ws + off); off += (size_t)PLEN * 2;
  ushort_t* WheadT = (ushort_t*)(ws + off); off += (size_t)PLEN * 2;
  float* part = (float*)(ws + off);         off += 1024 * 4;
  float* av = (float*)(ws + off);           off += 1024 * 4;

  const int M = B_ * NPT;  // 8192

  prep_kernel<<<4096, 256, 0, stream>>>(pos, x, Wqkv, Wproj, Whead,
                                        idx, xbf, WqkvT, WprojT, WheadT, part);
  gemm_rf<0><<<3072, 64, 0, stream>>>(xbf, WqkvT, nullptr, nullptr,
                                      qkv, nullptr, nullptr, QKVW);
  attn_kernel<<<M, 256, 0, stream>>>(qkv, pos, idx, Wp0, bp0, Wp1, bp1, xcat);
  gemm_rf<1><<<1024, 64, 0, stream>>>(xcat, WprojT, bproj, nullptr,
                                      fp, part, nullptr, DIM_);
  msf_av_kernel<<<B_, 256, 0, stream>>>(part, Wfc1, bfc1, Wfc2, bfc2, av);
  gemm_rf<2><<<1024, 64, 0, stream>>>(xcat, WheadT, bhead, fp,
                                      out, nullptr, av, DIM_);
}